// Round 4
// baseline (476.399 us; speedup 1.0000x reference)
//
#include <hip/hip_runtime.h>
#include <hip/hip_bf16.h>

// SplineCNN round 19: eliminate the xWb round-trip (160MB write + 212MB
// random read per layer, the whole remaining cost). Reformulation:
//   msg_e = sum_s w_es * (x[src_e] @ W[slot_es])
// Bucket edges by base slot b=iu+5iv (25 buckets; the 4 slots per edge are
// determined by b). Per bucket, gathered x-rows (x = 6.4MB, L2/LLC
// resident) feed 16x16x32 MFMA against the 4 shared W tiles; per-row
// weighted epilogue accumulates msg in fp32; msg row stored once at its
// dst-CSR position -> the max pass reads msg LINEARLY. Dense 25-tile gemm
// deleted; small root gemm kept. Per-layer HBM ~476MB -> ~240MB and no
// random reads of a >LLC working set.
// Pipeline: prep -> hist(deg+bucket) -> scans -> bucket_setup(prefix+pad)
// -> scatter_recs (bucket-sorted 16B records, block-aggregated counting
// sort) -> [root_gemm -> spline_mm -> edge_max] x2 -> final_mfma.

typedef short  bf16x8 __attribute__((ext_vector_type(8)));
typedef float  f32x4  __attribute__((ext_vector_type(4)));
typedef int    i32x4  __attribute__((ext_vector_type(4)));

__device__ __forceinline__ float bf2f(ushort u) {
    return __uint_as_float((uint)u << 16);
}
__device__ __forceinline__ ushort f2bf(float f) {   // round-to-nearest-even
    uint u = __float_as_uint(f);
    return (ushort)((u + 0x7FFF + ((u >> 16) & 1)) >> 16);
}

// ---------------- fused prep --------------------------------------------
// [0,nx): xb = bf16(x); [+nw): WtA; [+nw): WtB; [+nfw): fwT; [+Nz): dstat=0
__global__ __launch_bounds__(256) void prep(
    const float* __restrict__ x, ushort* __restrict__ xb, int nx,
    const float* __restrict__ W1, const float* __restrict__ r1, ushort* __restrict__ WtA,
    const float* __restrict__ W2, const float* __restrict__ r2, ushort* __restrict__ WtB,
    const float* __restrict__ fw, ushort* __restrict__ fwT,
    int* __restrict__ dstat, int Nz)
{
    const int nw = 26 * 4096, nfw = 3 * 4096;
    int idx = blockIdx.x * 256 + threadIdx.x;
    if (idx < nx) { xb[idx] = f2bf(x[idx]); return; }
    idx -= nx;
    if (idx < nw) {
        int tile = idx >> 12, rem = idx & 4095, o = rem >> 6, i = rem & 63;
        WtA[idx] = f2bf(tile < 25 ? W1[tile * 4096 + i * 64 + o] : r1[i * 64 + o]);
        return;
    }
    idx -= nw;
    if (idx < nw) {
        int tile = idx >> 12, rem = idx & 4095, o = rem >> 6, i = rem & 63;
        WtB[idx] = f2bf(tile < 25 ? W2[tile * 4096 + i * 64 + o] : r2[i * 64 + o]);
        return;
    }
    idx -= nw;
    if (idx < nfw) {
        int t = idx >> 12, rem = idx & 4095, o = rem >> 6, k = rem & 63;
        fwT[idx] = f2bf(fw[(t * 64 + k) * 64 + o]);
        return;
    }
    idx -= nfw;
    if (idx < Nz) dstat[idx] = 0;
}

// ---------------- histograms: dst degree + bucket counts ----------------
__global__ __launch_bounds__(256) void hist_deg(
    const int* __restrict__ ei, const float* __restrict__ attr,
    int* __restrict__ deg, int* __restrict__ bcount, int E)
{
    __shared__ int lb[25];
    int t = threadIdx.x;
    if (t < 25) lb[t] = 0;
    __syncthreads();
    int e = blockIdx.x * 256 + t;
    if (e < E) {
        atomicAdd(&deg[ei[E + e]], 1);
        float u = attr[2 * e] * 4.f;
        float v = attr[2 * e + 1] * 4.f;
        int iu = (int)floorf(u);  iu = iu < 0 ? 0 : (iu > 4 ? 4 : iu);
        int iv = (int)floorf(v);  iv = iv < 0 ? 0 : (iv > 4 ? 4 : iv);
        atomicAdd(&lb[iu + 5 * iv], 1);
    }
    __syncthreads();
    if (t < 25 && lb[t] > 0) atomicAdd(&bcount[t], lb[t]);
}

// ---------------- CSR scan chain ----------------------------------------
__global__ __launch_bounds__(1024) void scan_block(
    const int* __restrict__ deg, int* __restrict__ inc,
    int* __restrict__ partial, int N)
{
    __shared__ int s[1024];
    int i = blockIdx.x * 1024 + threadIdx.x;
    int v = (i < N) ? deg[i] : 0;
    s[threadIdx.x] = v;
    __syncthreads();
    for (int off = 1; off < 1024; off <<= 1) {
        int t = (threadIdx.x >= off) ? s[threadIdx.x - off] : 0;
        __syncthreads();
        s[threadIdx.x] += t;
        __syncthreads();
    }
    if (i < N) inc[i] = s[threadIdx.x];
    if (threadIdx.x == 1023) partial[blockIdx.x] = s[1023];
}

__global__ void scan_partial(int* __restrict__ partial, int nb)  // nb <= 64
{
    __shared__ int s[64];
    int t = threadIdx.x;
    int v = (t < nb) ? partial[t] : 0;
    s[t] = v;
    __syncthreads();
    for (int off = 1; off < 64; off <<= 1) {
        int x = (t >= off) ? s[t - off] : 0;
        __syncthreads();
        s[t] += x;
        __syncthreads();
    }
    if (t < nb) partial[t] = s[t] - v;   // exclusive block offsets
}

__global__ __launch_bounds__(1024) void scan_finalize(
    const int* __restrict__ deg, const int* __restrict__ inc,
    const int* __restrict__ partial, int* __restrict__ row_ptr,
    int* __restrict__ cursor, int N)
{
    int i = blockIdx.x * 1024 + threadIdx.x;
    if (i >= N) return;
    int v = inc[i] + partial[blockIdx.x];
    row_ptr[i + 1] = v;
    cursor[i] = v - deg[i];
    if (i == 0) row_ptr[0] = 0;
}

// ---------------- bucket prefix (padded to 64) + pad-fill ---------------
__global__ void bucket_setup(const int* __restrict__ bcount,
                             int* __restrict__ boff, uint4* __restrict__ recs, int E)
{
    __shared__ int sb[26], sc[25];
    int t = threadIdx.x;
    if (t == 0) {
        int acc = 0;
        for (int b = 0; b < 25; ++b) {
            sb[b] = acc; boff[b] = acc; sc[b] = bcount[b];
            acc += (bcount[b] + 63) & ~63;
        }
        sb[25] = acc; boff[25] = acc;
    }
    __syncthreads();
    uint4 z = make_uint4(0u, 0u, 0u, (uint)E);   // w=0, pos=scratch row E
    for (int b = 0; b < 25; ++b) {
        int start = sb[b] + sc[b], end = sb[b + 1];
        for (int i = start + t; i < end; i += 64) recs[i] = z;
    }
}

// ---------------- scatter: bucket-sorted records ------------------------
// rec = {src*128 (byte off into bf16 row), wlo, whi, pos (dst-CSR row)}
__global__ __launch_bounds__(256) void scatter_recs(
    const int* __restrict__ ei, const float* __restrict__ attr,
    int* __restrict__ cursor, int* __restrict__ bcur,
    const int* __restrict__ boff, uint4* __restrict__ recs, int E)
{
    __shared__ int lcnt[25], lbase[25];
    int t = threadIdx.x;
    if (t < 25) lcnt[t] = 0;
    __syncthreads();
    int e = blockIdx.x * 256 + t;
    bool act = e < E;
    int b = 0, rank = 0, src = 0, dst = 0;
    float fu = 0.f, fv = 0.f;
    if (act) {
        src = ei[e]; dst = ei[E + e];
        float u = attr[2 * e] * 4.f;
        float v = attr[2 * e + 1] * 4.f;
        float lu = floorf(u), lv = floorf(v);
        fu = u - lu; fv = v - lv;
        int iu = (int)lu;  iu = iu < 0 ? 0 : (iu > 4 ? 4 : iu);
        int iv = (int)lv;  iv = iv < 0 ? 0 : (iv > 4 ? 4 : iv);
        b = iu + 5 * iv;
        rank = atomicAdd(&lcnt[b], 1);
    }
    __syncthreads();
    if (t < 25 && lcnt[t] > 0) lbase[t] = atomicAdd(&bcur[t], lcnt[t]);
    __syncthreads();
    if (act) {
        uint wlo = (uint)f2bf((1.f - fu) * (1.f - fv)) | ((uint)f2bf((1.f - fu) * fv) << 16);
        uint whi = (uint)f2bf(fu * (1.f - fv)) | ((uint)f2bf(fu * fv) << 16);
        int pos = atomicAdd(&cursor[dst], 1);
        int rpos = boff[b] + lbase[b] + rank;
        i32x4 pk = {src * 128, (int)wlo, (int)whi, pos};
        __builtin_nontemporal_store(pk, (i32x4*)(recs + rpos));
    }
}

// ---------------- root gemm: xRoot = bf16(A @ Wt[25]) -------------------
__global__ __launch_bounds__(256) void root_gemm(
    const ushort* __restrict__ A, const ushort* __restrict__ Wt,
    ushort* __restrict__ xRoot, int mtiles)
{
    const int wave = threadIdx.x >> 6;
    const int lane = threadIdx.x & 63;
    const int l16 = lane & 15;
    const int half = lane >> 4;
    const ushort* btile = Wt + (size_t)25 * 4096;
    bf16x8 b0[4], b1[4];
    #pragma unroll
    for (int s = 0; s < 4; ++s) {
        const ushort* brow = btile + (size_t)(s * 16 + l16) * 64;
        b0[s] = *(const bf16x8*)(brow + half * 8);
        b1[s] = *(const bf16x8*)(brow + 32 + half * 8);
    }
    const int mt_base = blockIdx.x * 8;
    const int nit = (mtiles - mt_base) < 8 ? (mtiles - mt_base) : 8;
    for (int it = 0; it < nit; ++it) {
        const int m_base = (mt_base + it) * 64 + wave * 16;
        const ushort* arow = A + (size_t)(m_base + l16) * 64;
        bf16x8 a0 = *(const bf16x8*)(arow + half * 8);
        bf16x8 a1 = *(const bf16x8*)(arow + 32 + half * 8);
        f32x4 acc[4];
        #pragma unroll
        for (int s = 0; s < 4; ++s) {
            acc[s] = (f32x4){0.f, 0.f, 0.f, 0.f};
            acc[s] = __builtin_amdgcn_mfma_f32_16x16x32_bf16(a0, b0[s], acc[s], 0, 0, 0);
            acc[s] = __builtin_amdgcn_mfma_f32_16x16x32_bf16(a1, b1[s], acc[s], 0, 0, 0);
        }
        #pragma unroll
        for (int s = 0; s < 4; ++s)
            #pragma unroll
            for (int r = 0; r < 4; ++r)
                xRoot[(size_t)(m_base + half * 4 + r) * 64 + s * 16 + l16] = f2bf(acc[s][r]);
    }
}

// ---------------- phase A: bucketed spline matmul -----------------------
// Wave owns one 64-record tile (all same bucket). Per 16-edge sub-tile:
// gather x rows -> LDS -> A-frags; for each of 4 slots: B-frags from Wt
// (L2), C = A@B via MFMA, msg += w[row][slot]*C; bf16 -> LDS slice ->
// 128B row store at dst-CSR pos (nt). Barrier-free (per-wave LDS).
struct ShA {
    int    srcS[64];
    int    posS[64];
    float4 wS[64];
    ushort xg[16][72];
    ushort cs[16][72];
};

__global__ __launch_bounds__(256) void spline_mm(
    const ushort* __restrict__ X, const ushort* __restrict__ Wt,
    const uint4* __restrict__ recs, const int* __restrict__ boff,
    ushort* __restrict__ msg)
{
    __shared__ ShA sh[4];
    const int wave = threadIdx.x >> 6;
    const int lane = threadIdx.x & 63;
    const int tile = blockIdx.x * 4 + wave;
    const int t64 = tile * 64;
    if (t64 >= boff[25]) return;
    ShA& S = sh[wave];

    // bucket of this tile (boff non-decreasing; empty buckets skipped)
    int b = 0;
    #pragma unroll
    for (int i = 1; i < 25; ++i) b += (t64 >= boff[i]) ? 1 : 0;
    const int iu = b % 5, iv = b / 5;
    const int iu1 = (iu + 1 > 4) ? 4 : iu + 1;
    const int iv1 = (iv + 1 > 4) ? 4 : iv + 1;
    const int slot[4] = {iu + 5 * iv, iu + 5 * iv1, iu1 + 5 * iv, iu1 + 5 * iv1};

    // stage 64 records
    {
        uint4 r = recs[t64 + lane];
        S.srcS[lane] = (int)r.x;
        S.posS[lane] = (int)r.w;
        S.wS[lane] = make_float4(bf2f((ushort)(r.y & 0xffff)), bf2f((ushort)(r.y >> 16)),
                                 bf2f((ushort)(r.z & 0xffff)), bf2f((ushort)(r.z >> 16)));
    }

    const int l16 = lane & 15, half = lane >> 4;
    const int rr = lane >> 2, q = lane & 3;
    const char* xp = (const char*)X;

    for (int rt = 0; rt < 4; ++rt) {
        // gather 16 x-rows (128B each; 4 lanes x 2 x uint4 per row)
        {
            int so = S.srcS[rt * 16 + rr];
            uint4 v0 = *(const uint4*)(xp + so + q * 16);
            uint4 v1 = *(const uint4*)(xp + so + q * 16 + 64);
            *(uint4*)&S.xg[rr][q * 8] = v0;
            *(uint4*)&S.xg[rr][q * 8 + 32] = v1;
        }
        // A-frags (row = local edge l16)
        bf16x8 a0 = *(const bf16x8*)&S.xg[l16][half * 8];
        bf16x8 a1 = *(const bf16x8*)&S.xg[l16][32 + half * 8];
        // weights for my 4 rows
        float4 w4[4];
        #pragma unroll
        for (int r = 0; r < 4; ++r) w4[r] = S.wS[rt * 16 + half * 4 + r];

        f32x4 macc[4];
        #pragma unroll
        for (int s = 0; s < 4; ++s) macc[s] = (f32x4){0.f, 0.f, 0.f, 0.f};

        #pragma unroll
        for (int sl = 0; sl < 4; ++sl) {
            const ushort* btile = Wt + (size_t)slot[sl] * 4096;
            #pragma unroll
            for (int s = 0; s < 4; ++s) {
                const ushort* brow = btile + (size_t)(s * 16 + l16) * 64;
                bf16x8 b0 = *(const bf16x8*)(brow + half * 8);
                bf16x8 b1 = *(const bf16x8*)(brow + 32 + half * 8);
                f32x4 c = (f32x4){0.f, 0.f, 0.f, 0.f};
                c = __builtin_amdgcn_mfma_f32_16x16x32_bf16(a0, b0, c, 0, 0, 0);
                c = __builtin_amdgcn_mfma_f32_16x16x32_bf16(a1, b1, c, 0, 0, 0);
                const float ws0 = (sl == 0) ? w4[0].x : (sl == 1) ? w4[0].y : (sl == 2) ? w4[0].z : w4[0].w;
                const float ws1 = (sl == 0) ? w4[1].x : (sl == 1) ? w4[1].y : (sl == 2) ? w4[1].z : w4[1].w;
                const float ws2 = (sl == 0) ? w4[2].x : (sl == 1) ? w4[2].y : (sl == 2) ? w4[2].z : w4[2].w;
                const float ws3 = (sl == 0) ? w4[3].x : (sl == 1) ? w4[3].y : (sl == 2) ? w4[3].z : w4[3].w;
                macc[s][0] = fmaf(ws0, c[0], macc[s][0]);
                macc[s][1] = fmaf(ws1, c[1], macc[s][1]);
                macc[s][2] = fmaf(ws2, c[2], macc[s][2]);
                macc[s][3] = fmaf(ws3, c[3], macc[s][3]);
            }
        }

        // stage bf16 msg rows -> coalesced 128B stores at dst-CSR pos
        #pragma unroll
        for (int s = 0; s < 4; ++s)
            #pragma unroll
            for (int r = 0; r < 4; ++r)
                S.cs[half * 4 + r][s * 16 + l16] = f2bf(macc[s][r]);
        #pragma unroll
        for (int i2 = 0; i2 < 2; ++i2) {
            int idx = i2 * 64 + lane;
            int row = idx >> 3, seg = idx & 7;
            i32x4 v = *(const i32x4*)&S.cs[row][seg * 8];
            int pos = S.posS[rt * 16 + row];
            __builtin_nontemporal_store(v, (i32x4*)(msg + (size_t)pos * 64 + seg * 8));
        }
    }
}

// ---------------- phase B: linear segment-max + root + bias + relu ------
__global__ __launch_bounds__(256) void edge_max(
    const ushort* __restrict__ msg, const int* __restrict__ row_ptr,
    const ushort* __restrict__ xRoot, const float* __restrict__ bias,
    ushort* __restrict__ outb, int N)
{
    const int wv = __builtin_amdgcn_readfirstlane(threadIdx.x >> 6);
    const int d = blockIdx.x * 4 + wv;
    const int lane = threadIdx.x & 63;
    if (d >= N) return;
    const int e0 = __builtin_amdgcn_readfirstlane(row_ptr[d]);
    const int e1 = __builtin_amdgcn_readfirstlane(row_ptr[d + 1]);
    const int cnt = e1 - e0;
    const ushort* mp = msg + (size_t)e0 * 64 + lane;

    float vmax = -__builtin_inff();
    int i = 0;
    for (; i + 4 <= cnt; i += 4) {
        float m0 = bf2f(mp[(size_t)(i + 0) * 64]);
        float m1 = bf2f(mp[(size_t)(i + 1) * 64]);
        float m2 = bf2f(mp[(size_t)(i + 2) * 64]);
        float m3 = bf2f(mp[(size_t)(i + 3) * 64]);
        vmax = fmaxf(vmax, fmaxf(fmaxf(m0, m1), fmaxf(m2, m3)));
    }
    for (; i < cnt; ++i) vmax = fmaxf(vmax, bf2f(mp[(size_t)i * 64]));
    if (cnt == 0) vmax = 0.f;          // segment_max(-inf) -> 0
    float val = vmax + bf2f(xRoot[(size_t)d * 64 + lane]) + bias[lane];
    val = fmaxf(val, 0.f);
    outb[(size_t)d * 64 + lane] = f2bf(val);
}

// ---------------- final: out = [xb|x1b|x2b] @ fwT + fb (bf16 MFMA) ------
__global__ __launch_bounds__(256) void final_mfma(
    const ushort* __restrict__ xb, const ushort* __restrict__ x1b,
    const ushort* __restrict__ x2b, const ushort* __restrict__ fwT,
    const float* __restrict__ fb, float* __restrict__ out, int M)
{
    const int wave = threadIdx.x >> 6;
    const int lane = threadIdx.x & 63;
    const int l16 = lane & 15;
    const int half = lane >> 4;
    const int m_base = blockIdx.x * 64 + wave * 16;
    const ushort* srcs[3] = {xb, x1b, x2b};

    f32x4 acc[4];
    #pragma unroll
    for (int s = 0; s < 4; ++s) acc[s] = (f32x4){0.f, 0.f, 0.f, 0.f};

    #pragma unroll
    for (int t = 0; t < 3; ++t) {
        const ushort* arow = srcs[t] + (size_t)(m_base + l16) * 64;
        bf16x8 a0 = *(const bf16x8*)(arow + half * 8);
        bf16x8 a1 = *(const bf16x8*)(arow + 32 + half * 8);
        const ushort* btile = fwT + (size_t)t * 4096;
        #pragma unroll
        for (int s = 0; s < 4; ++s) {
            const ushort* brow = btile + (size_t)(s * 16 + l16) * 64;
            bf16x8 b0 = *(const bf16x8*)(brow + half * 8);
            bf16x8 b1 = *(const bf16x8*)(brow + 32 + half * 8);
            acc[s] = __builtin_amdgcn_mfma_f32_16x16x32_bf16(a0, b0, acc[s], 0, 0, 0);
            acc[s] = __builtin_amdgcn_mfma_f32_16x16x32_bf16(a1, b1, acc[s], 0, 0, 0);
        }
    }

    #pragma unroll
    for (int s = 0; s < 4; ++s) {
        int o = s * 16 + l16;
        float b = fb[o];
        #pragma unroll
        for (int r = 0; r < 4; ++r) {
            int m = m_base + half * 4 + r;
            if (m < M) out[(size_t)m * 64 + o] = acc[s][r] + b;
        }
    }
}

extern "C" void kernel_launch(void* const* d_in, const int* in_sizes, int n_in,
                              void* d_out, int out_size, void* d_ws, size_t ws_size,
                              hipStream_t stream)
{
    const float* x    = (const float*)d_in[0];
    const int*   ei   = (const int*)d_in[1];
    const float* attr = (const float*)d_in[2];
    const float* W1   = (const float*)d_in[3];
    const float* r1   = (const float*)d_in[4];
    const float* b1   = (const float*)d_in[5];
    const float* W2   = (const float*)d_in[6];
    const float* r2   = (const float*)d_in[7];
    const float* b2   = (const float*)d_in[8];
    const float* fw   = (const float*)d_in[9];
    const float* fb   = (const float*)d_in[10];
    float* out = (float*)d_out;

    const int N = in_sizes[0] / 64;
    const int E = in_sizes[1] / 2;
    const int mtiles = (N + 63) / 64;
    const int Npad = mtiles * 64;

    // workspace carve (~140 MB)
    char* p = (char*)d_ws;
    auto alloc = [&](size_t bytes) { void* q = p; p += (bytes + 255) & ~(size_t)255; return q; };
    uint4*  recs   = (uint4*)alloc((size_t)(E + 1600) * 16);
    ushort* msg    = (ushort*)alloc((size_t)(E + 1) * 64 * 2);
    ushort* xRoot  = (ushort*)alloc((size_t)Npad * 64 * 2);
    ushort* xb     = (ushort*)alloc((size_t)Npad * 64 * 2);
    ushort* x1b    = (ushort*)alloc((size_t)Npad * 64 * 2);
    ushort* x2b    = (ushort*)alloc((size_t)Npad * 64 * 2);
    ushort* WtA    = (ushort*)alloc((size_t)26 * 4096 * 2);
    ushort* WtB    = (ushort*)alloc((size_t)26 * 4096 * 2);
    ushort* fwT    = (ushort*)alloc((size_t)3 * 4096 * 2);
    int*    dstat  = (int*)alloc((size_t)(N + 64) * 4);   // deg | bcount | bcur
    int*    cursor = (int*)alloc((size_t)N * 4);
    int*    rowp   = (int*)alloc((size_t)(N + 1) * 4);
    int*    tmpinc = (int*)alloc((size_t)N * 4);
    int*    part   = (int*)alloc(64 * 4);
    int*    boff   = (int*)alloc(32 * 4);

    int* deg    = dstat;
    int* bcount = dstat + N;
    int* bcur   = dstat + N + 25;

    const int nb = (N + 1023) / 1024;   // <= 64 for N <= 65536

    // fused prep: xb, WtA, WtB, fwT, zero deg+bcount+bcur
    const int Nz = N + 50;
    const int nprep = N * 64 + 2 * 26 * 4096 + 3 * 4096 + Nz;
    prep<<<(nprep + 255) / 256, 256, 0, stream>>>(
        x, xb, N * 64, W1, r1, WtA, W2, r2, WtB, fw, fwT, dstat, Nz);

    // histograms + CSR scan chain + bucket setup
    hist_deg<<<(E + 255) / 256, 256, 0, stream>>>(ei, attr, deg, bcount, E);
    scan_block<<<nb, 1024, 0, stream>>>(deg, tmpinc, part, N);
    scan_partial<<<1, 64, 0, stream>>>(part, nb);
    scan_finalize<<<nb, 1024, 0, stream>>>(deg, tmpinc, part, rowp, cursor, N);
    bucket_setup<<<1, 64, 0, stream>>>(bcount, boff, recs, E);

    // bucket-sorted record scatter
    scatter_recs<<<(E + 255) / 256, 256, 0, stream>>>(
        ei, attr, cursor, bcur, boff, recs, E);

    const int gy = (mtiles + 7) / 8;
    const int nblkA = (E + 1600 + 255) / 256;

    // layer 1
    root_gemm<<<gy, 256, 0, stream>>>(xb, WtA, xRoot, mtiles);
    spline_mm<<<nblkA, 256, 0, stream>>>(xb, WtA, recs, boff, msg);
    edge_max<<<(N + 3) / 4, 256, 0, stream>>>(msg, rowp, xRoot, b1, x1b, N);

    // layer 2
    root_gemm<<<gy, 256, 0, stream>>>(x1b, WtB, xRoot, mtiles);
    spline_mm<<<nblkA, 256, 0, stream>>>(x1b, WtB, recs, boff, msg);
    edge_max<<<(N + 3) / 4, 256, 0, stream>>>(msg, rowp, xRoot, b2, x2b, N);

    // final: bf16 MFMA, fp32 out + fb
    final_mfma<<<mtiles, 256, 0, stream>>>(xb, x1b, x2b, fwT, fb, out, N);
}